// Round 6
// baseline (2070.408 us; speedup 1.0000x reference)
//
#include <hip/hip_runtime.h>
#include <stdint.h>

// GCN 2-hop, R6: ONE plain-launch mega-kernel (512 blocks x 256 thr,
// __launch_bounds__(256,2) => 2 blocks/CU co-resident by construction),
// manual device-scope atomic grid barrier (per-phase counters, memset each
// call). Dataflow (S@x)@W from R4:
//   A: zero deg/cnt + x->bf16 + W transposes
//   B: edge accumulation (deg,cnt atomics)
//   C: dinv=rsqrt(1+deg) (all blocks) || block0: scan cnt->rowptr/cursor
//   D: CSR fill (srcs, norms)
//   E: Sx  = S @ xb   (gather, 128d)
//   F: h1  = LN(relu(Sx@W1+b1) + x@Wres + bres)   (MFMA, fused LN)
//   G: Sh1 = S @ h1   (gather, 256d)
//   H: out = LN(Sh1@W2 + b2 + h1)                 (MFMA, fused LN)

constexpr int DIN  = 128;
constexpr int DH   = 256;
constexpr int GRID = 512;               // 2 blocks/CU on 256-CU MI355X
#define LN_EPS 1e-5f

typedef __attribute__((ext_vector_type(8))) short bf16x8;  // 16 B
typedef __attribute__((ext_vector_type(4))) short bf16x4;  // 8 B
typedef __attribute__((ext_vector_type(4))) float f32x4;

__device__ __forceinline__ short f2bf(float f) {
  union { float f; unsigned u; } v; v.f = f;
  unsigned r = v.u + 0x7fffu + ((v.u >> 16) & 1u);  // RNE
  return (short)(r >> 16);
}
__device__ __forceinline__ float bf2f(short b) {
  union { unsigned u; float f; } v; v.u = ((unsigned)(unsigned short)b) << 16;
  return v.f;
}

// Device-scope grid barrier: one counter per barrier point (bar[] zeroed by
// hipMemsetAsync before launch). All GRID blocks are co-resident (see launch
// bounds math above), so the spin cannot deadlock. __threadfence() = agent
// scope: makes prior writes visible across XCD L2s (gfx950 memory model).
__device__ __forceinline__ void gsync(int* bar, int idx, int nb) {
  __syncthreads();
  if (threadIdx.x == 0) {
    __threadfence();
    __hip_atomic_fetch_add(bar + idx, 1, __ATOMIC_ACQ_REL,
                           __HIP_MEMORY_SCOPE_AGENT);
    while (__hip_atomic_load(bar + idx, __ATOMIC_ACQUIRE,
                             __HIP_MEMORY_SCOPE_AGENT) < nb)
      __builtin_amdgcn_s_sleep(2);
    __threadfence();
  }
  __syncthreads();
}

// edge_index may be int32 (JAX x64 off) or int64: sample odd 32-bit words of
// the src half; all-zero <=> int64. Call with the wave converged.
__device__ __forceinline__ int probe_m64(const unsigned* ei, int E) {
  int lane = threadIdx.x & 63;
  long long stride = (E >= 64) ? (E / 64) : 1;
  long long li = (long long)lane * stride;
  if (li >= E) li = 0;
  unsigned v = ei[2 * li + 1];
  return __ballot(v != 0u) == 0ull;
}

__device__ __forceinline__ int eidx(const void* ei, long long e, int m64) {
  return m64 ? (int)((const long long*)ei)[e] : ((const int*)ei)[e];
}

// ---- per-wave GEMM+LN bodies (16 rows x 256 cols, 16 mfma_16x16x32 frags) --

__device__ __forceinline__ void gemm_ln1_wave(
    int bm, int lane, const short* __restrict__ Sx,
    const short* __restrict__ xb, const short* __restrict__ W1t,
    const short* __restrict__ Wrt, const float* __restrict__ b1,
    const float* __restrict__ bres, const float* __restrict__ g1,
    const float* __restrict__ be1, short* __restrict__ h1b, int M) {
  int lr = lane & 15, lg = lane >> 4;
  int ar = min(bm + lr, M - 1);
  f32x4 acc[16] = {};
#pragma unroll
  for (int ks = 0; ks < 4; ++ks) {
    bf16x8 a = *(const bf16x8*)(Sx + (long long)ar * DIN + ks * 32 + lg * 8);
#pragma unroll
    for (int ni = 0; ni < 16; ++ni) {
      bf16x8 b = *(const bf16x8*)(W1t + (ni * 16 + lr) * DIN + ks * 32 + lg * 8);
      acc[ni] = __builtin_amdgcn_mfma_f32_16x16x32_bf16(a, b, acc[ni], 0, 0, 0);
    }
  }
#pragma unroll
  for (int ni = 0; ni < 16; ++ni) {
    int col = ni * 16 + lr;
    float bb = b1[col], br = bres[col];
#pragma unroll
    for (int j = 0; j < 4; ++j)
      acc[ni][j] = fmaxf(acc[ni][j] + bb, 0.f) + br;
  }
#pragma unroll
  for (int ks = 0; ks < 4; ++ks) {
    bf16x8 a = *(const bf16x8*)(xb + (long long)ar * DIN + ks * 32 + lg * 8);
#pragma unroll
    for (int ni = 0; ni < 16; ++ni) {
      bf16x8 b = *(const bf16x8*)(Wrt + (ni * 16 + lr) * DIN + ks * 32 + lg * 8);
      acc[ni] = __builtin_amdgcn_mfma_f32_16x16x32_bf16(a, b, acc[ni], 0, 0, 0);
    }
  }
#pragma unroll
  for (int j = 0; j < 4; ++j) {
    int r = bm + lg * 4 + j;
    float s1 = 0.f, s2 = 0.f;
#pragma unroll
    for (int ni = 0; ni < 16; ++ni) {
      float v = acc[ni][j];
      s1 += v; s2 += v * v;
    }
#pragma unroll
    for (int m = 1; m < 16; m <<= 1) {
      s1 += __shfl_xor(s1, m, 64);
      s2 += __shfl_xor(s2, m, 64);
    }
    float mu = s1 * (1.f / 256.f);
    float rs = rsqrtf(s2 * (1.f / 256.f) - mu * mu + LN_EPS);
    if (r < M) {
#pragma unroll
      for (int ni = 0; ni < 16; ++ni) {
        int col = ni * 16 + lr;
        float y = (acc[ni][j] - mu) * rs * g1[col] + be1[col];
        h1b[(long long)r * DH + col] = f2bf(y);
      }
    }
  }
}

__device__ __forceinline__ void gemm_ln2_wave(
    int bm, int lane, const short* __restrict__ Sh1,
    const short* __restrict__ h1b, const short* __restrict__ W2t,
    const float* __restrict__ b2, const float* __restrict__ g2,
    const float* __restrict__ be2, float* __restrict__ out, int M) {
  int lr = lane & 15, lg = lane >> 4;
  int ar = min(bm + lr, M - 1);
  f32x4 acc[16] = {};
#pragma unroll
  for (int ks = 0; ks < 8; ++ks) {
    bf16x8 a = *(const bf16x8*)(Sh1 + (long long)ar * DH + ks * 32 + lg * 8);
#pragma unroll
    for (int ni = 0; ni < 16; ++ni) {
      bf16x8 b = *(const bf16x8*)(W2t + (ni * 16 + lr) * DH + ks * 32 + lg * 8);
      acc[ni] = __builtin_amdgcn_mfma_f32_16x16x32_bf16(a, b, acc[ni], 0, 0, 0);
    }
  }
#pragma unroll
  for (int j = 0; j < 4; ++j) {
    int rr = min(bm + lg * 4 + j, M - 1);
#pragma unroll
    for (int ni = 0; ni < 16; ++ni) {
      int col = ni * 16 + lr;
      acc[ni][j] += b2[col] + bf2f(h1b[(long long)rr * DH + col]);
    }
  }
#pragma unroll
  for (int j = 0; j < 4; ++j) {
    int r = bm + lg * 4 + j;
    float s1 = 0.f, s2 = 0.f;
#pragma unroll
    for (int ni = 0; ni < 16; ++ni) {
      float v = acc[ni][j];
      s1 += v; s2 += v * v;
    }
#pragma unroll
    for (int m = 1; m < 16; m <<= 1) {
      s1 += __shfl_xor(s1, m, 64);
      s2 += __shfl_xor(s2, m, 64);
    }
    float mu = s1 * (1.f / 256.f);
    float rs = rsqrtf(s2 * (1.f / 256.f) - mu * mu + LN_EPS);
    if (r < M) {
#pragma unroll
      for (int ni = 0; ni < 16; ++ni) {
        int col = ni * 16 + lr;
        out[(long long)r * DH + col] = (acc[ni][j] - mu) * rs * g2[col] + be2[col];
      }
    }
  }
}

// ------------------------------- mega kernel -------------------------------

__global__ __launch_bounds__(256, 2) void k_mega(
    const float* __restrict__ x, const void* ei, const float* __restrict__ ew,
    const float* __restrict__ W1, const float* __restrict__ b1,
    const float* __restrict__ W2, const float* __restrict__ b2,
    const float* __restrict__ Wres, const float* __restrict__ bres,
    const float* __restrict__ g1, const float* __restrict__ be1,
    const float* __restrict__ g2, const float* __restrict__ be2,
    short* __restrict__ xb, short* __restrict__ W1t, short* __restrict__ Wrt,
    short* __restrict__ W2t, short* __restrict__ Sx, short* __restrict__ h1b,
    short* __restrict__ Sh1, float* __restrict__ deg, int* __restrict__ cnt,
    int* __restrict__ rowptr, int* __restrict__ cursor, int* __restrict__ srcs,
    float* __restrict__ norms, int* bar, float* __restrict__ out,
    int N, int E) {
  __shared__ int ws4[4];

  const int NT = GRID * 256;
  const int NWAVES = GRID * 4;
  const int g = blockIdx.x * 256 + threadIdx.x;
  const int lane = threadIdx.x & 63;
  const int wv = threadIdx.x >> 6;
  const int wid = (blockIdx.x << 2) | wv;
  const int m64 = probe_m64((const unsigned*)ei, E);  // converged here

  // ---- phase A: zero deg/cnt, x->bf16, weight transposes ----
  for (int i = g; i < N; i += NT) { deg[i] = 0.f; cnt[i] = 0; }
  const int NXV = N * DIN / 8;
  for (int i = g; i < NXV; i += NT) {
    f32x4 a = ((const f32x4*)x)[i * 2];
    f32x4 b = ((const f32x4*)x)[i * 2 + 1];
    bf16x8 o;
    o[0] = f2bf(a[0]); o[1] = f2bf(a[1]); o[2] = f2bf(a[2]); o[3] = f2bf(a[3]);
    o[4] = f2bf(b[0]); o[5] = f2bf(b[1]); o[6] = f2bf(b[2]); o[7] = f2bf(b[3]);
    ((bf16x8*)xb)[i] = o;
  }
  const int NW = DIN * DH, NW2 = DH * DH;
  for (int i = g; i < NW; i += NT) {
    int n = i / DIN, k = i % DIN;
    W1t[i] = f2bf(W1[k * DH + n]);
    Wrt[i] = f2bf(Wres[k * DH + n]);
  }
  for (int i = g; i < NW2; i += NT) {
    int n = i / DH, k = i % DH;
    W2t[i] = f2bf(W2[k * DH + n]);
  }
  gsync(bar, 0, GRID);

  // ---- phase B: edge accumulation ----
  for (int e = g; e < E; e += NT) {
    int d = eidx(ei, (long long)E + e, m64);
    atomicAdd(&deg[d], ew[e]);
    atomicAdd(&cnt[d], 1);
  }
  gsync(bar, 1, GRID);

  // ---- phase C: dinv (all blocks) || scan (block 0) ----
  for (int i = g; i < N; i += NT) deg[i] = rsqrtf(1.0f + deg[i]);
  if (blockIdx.x == 0) {
    const int chunk = (N + 255) >> 8;
    int t = threadIdx.x;
    int base = t * chunk;
    int tot = 0;
    for (int j = 0; j < chunk; ++j) {
      int i = base + j;
      if (i < N) tot += cnt[i];
    }
    int sc = tot;
#pragma unroll
    for (int off = 1; off < 64; off <<= 1) {
      int tt = __shfl_up(sc, off, 64);
      if (lane >= off) sc += tt;
    }
    if (lane == 63) ws4[wv] = sc;
    __syncthreads();
    int add = 0;
    for (int k2 = 0; k2 < wv; ++k2) add += ws4[k2];
    int run = (sc - tot) + add;                 // exclusive prefix for thread
    if (t == 0) { rowptr[0] = 0; cursor[0] = 0; }
    for (int j = 0; j < chunk; ++j) {
      int i = base + j;
      if (i < N) {
        run += cnt[i];
        rowptr[i + 1] = run;
        cursor[i + 1] = run;
      }
    }
  }
  gsync(bar, 2, GRID);

  // ---- phase D: CSR fill ----
  for (int e = g; e < E; e += NT) {
    int s = eidx(ei, e, m64);
    int d = eidx(ei, (long long)E + e, m64);
    int p = atomicAdd(&cursor[d], 1);
    srcs[p] = s;
    norms[p] = deg[s] * ew[e] * deg[d];         // deg holds dinv now
  }
  gsync(bar, 3, GRID);

  // ---- phase E: Sx = S @ xb (128d gather; half-wave per edge) ----
  {
    int h = lane >> 5;
    int c = (lane & 31) * 4;
    for (int i = wid; i < N; i += NWAVES) {
      float a0 = 0.f, a1 = 0.f, a2 = 0.f, a3 = 0.f;
      int e = rowptr[i] + h, end = rowptr[i + 1];
      for (; e + 6 < end; e += 8) {
        int s0 = srcs[e], s1 = srcs[e + 2], s2 = srcs[e + 4], s3 = srcs[e + 6];
        float w0 = norms[e], w1 = norms[e + 2], w2 = norms[e + 4], w3 = norms[e + 6];
        bf16x4 v0 = *(const bf16x4*)(xb + (long long)s0 * DIN + c);
        bf16x4 v1 = *(const bf16x4*)(xb + (long long)s1 * DIN + c);
        bf16x4 v2 = *(const bf16x4*)(xb + (long long)s2 * DIN + c);
        bf16x4 v3 = *(const bf16x4*)(xb + (long long)s3 * DIN + c);
        a0 += w0 * bf2f(v0[0]) + w1 * bf2f(v1[0]) + w2 * bf2f(v2[0]) + w3 * bf2f(v3[0]);
        a1 += w0 * bf2f(v0[1]) + w1 * bf2f(v1[1]) + w2 * bf2f(v2[1]) + w3 * bf2f(v3[1]);
        a2 += w0 * bf2f(v0[2]) + w1 * bf2f(v1[2]) + w2 * bf2f(v2[2]) + w3 * bf2f(v3[2]);
        a3 += w0 * bf2f(v0[3]) + w1 * bf2f(v1[3]) + w2 * bf2f(v2[3]) + w3 * bf2f(v3[3]);
      }
      for (; e < end; e += 2) {
        int s = srcs[e];
        float w = norms[e];
        bf16x4 v = *(const bf16x4*)(xb + (long long)s * DIN + c);
        a0 += w * bf2f(v[0]); a1 += w * bf2f(v[1]);
        a2 += w * bf2f(v[2]); a3 += w * bf2f(v[3]);
      }
      a0 += __shfl_xor(a0, 32, 64); a1 += __shfl_xor(a1, 32, 64);
      a2 += __shfl_xor(a2, 32, 64); a3 += __shfl_xor(a3, 32, 64);
      if (h == 0) {
        float sw = deg[i] * deg[i];
        bf16x4 sv = *(const bf16x4*)(xb + (long long)i * DIN + c);
        bf16x4 o;
        o[0] = f2bf(a0 + sw * bf2f(sv[0]));
        o[1] = f2bf(a1 + sw * bf2f(sv[1]));
        o[2] = f2bf(a2 + sw * bf2f(sv[2]));
        o[3] = f2bf(a3 + sw * bf2f(sv[3]));
        *(bf16x4*)(Sx + (long long)i * DIN + c) = o;
      }
    }
  }
  gsync(bar, 4, GRID);

  // ---- phase F: h1 = LN(relu(Sx@W1+b1) + x@Wres + bres) ----
  {
    int T1 = (N + 15) >> 4;
    for (int t = wid; t < T1; t += NWAVES)
      gemm_ln1_wave(t * 16, lane, Sx, xb, W1t, Wrt, b1, bres, g1, be1, h1b, N);
  }
  gsync(bar, 5, GRID);

  // ---- phase G: Sh1 = S @ h1 (256d gather) ----
  {
    int h = lane >> 5;
    int c = (lane & 31) * 8;
    for (int i = wid; i < N; i += NWAVES) {
      float acc[8];
#pragma unroll
      for (int k = 0; k < 8; ++k) acc[k] = 0.f;
      int e = rowptr[i] + h, end = rowptr[i + 1];
      for (; e + 6 < end; e += 8) {
        int s0 = srcs[e], s1 = srcs[e + 2], s2 = srcs[e + 4], s3 = srcs[e + 6];
        float w0 = norms[e], w1 = norms[e + 2], w2 = norms[e + 4], w3 = norms[e + 6];
        bf16x8 v0 = *(const bf16x8*)(h1b + (long long)s0 * DH + c);
        bf16x8 v1 = *(const bf16x8*)(h1b + (long long)s1 * DH + c);
        bf16x8 v2 = *(const bf16x8*)(h1b + (long long)s2 * DH + c);
        bf16x8 v3 = *(const bf16x8*)(h1b + (long long)s3 * DH + c);
#pragma unroll
        for (int k = 0; k < 8; ++k)
          acc[k] += w0 * bf2f(v0[k]) + w1 * bf2f(v1[k]) +
                    w2 * bf2f(v2[k]) + w3 * bf2f(v3[k]);
      }
      for (; e < end; e += 2) {
        int s = srcs[e];
        float w = norms[e];
        bf16x8 v = *(const bf16x8*)(h1b + (long long)s * DH + c);
#pragma unroll
        for (int k = 0; k < 8; ++k) acc[k] += w * bf2f(v[k]);
      }
#pragma unroll
      for (int k = 0; k < 8; ++k) acc[k] += __shfl_xor(acc[k], 32, 64);
      if (h == 0) {
        float sw = deg[i] * deg[i];
        bf16x8 sv = *(const bf16x8*)(h1b + (long long)i * DH + c);
        bf16x8 o;
#pragma unroll
        for (int k = 0; k < 8; ++k) o[k] = f2bf(acc[k] + sw * bf2f(sv[k]));
        *(bf16x8*)(Sh1 + (long long)i * DH + c) = o;
      }
    }
  }
  gsync(bar, 6, GRID);

  // ---- phase H: out = LN(Sh1@W2 + b2 + h1) ----
  {
    int T1 = (N + 15) >> 4;
    for (int t = wid; t < T1; t += NWAVES)
      gemm_ln2_wave(t * 16, lane, Sh1, h1b, W2t, b2, g2, be2, out, N);
  }
}

// ---------------- launcher ----------------

extern "C" void kernel_launch(void* const* d_in, const int* in_sizes, int n_in,
                              void* d_out, int out_size, void* d_ws,
                              size_t ws_size, hipStream_t stream) {
  const float* x    = (const float*)d_in[0];
  const void*  ei   = d_in[1];
  const float* ew   = (const float*)d_in[2];
  const float* W1   = (const float*)d_in[3];
  const float* b1   = (const float*)d_in[4];
  const float* W2   = (const float*)d_in[5];
  const float* b2   = (const float*)d_in[6];
  const float* Wres = (const float*)d_in[7];
  const float* bres = (const float*)d_in[8];
  const float* g1   = (const float*)d_in[9];
  const float* be1  = (const float*)d_in[10];
  const float* g2   = (const float*)d_in[11];
  const float* be2  = (const float*)d_in[12];

  int N = in_sizes[0] / DIN;
  int E = in_sizes[2];

  char* ws = (char*)d_ws;
  auto alloc = [&](size_t bytes) -> char* {
    char* p = ws;
    ws += (bytes + 255) & ~(size_t)255;
    return p;
  };
  short* xb     = (short*)alloc((size_t)N * DIN * 2);
  short* W1t    = (short*)alloc((size_t)DIN * DH * 2);
  short* Wrt    = (short*)alloc((size_t)DIN * DH * 2);
  short* W2t    = (short*)alloc((size_t)DH * DH * 2);
  short* Sx     = (short*)alloc((size_t)N * DIN * 2);
  short* h1b    = (short*)alloc((size_t)N * DH * 2);
  short* Sh1    = (short*)alloc((size_t)N * DH * 2);
  float* deg    = (float*)alloc((size_t)N * 4);    // becomes dinv
  int*   cnt    = (int*)alloc((size_t)N * 4);
  int*   rowptr = (int*)alloc((size_t)(N + 1) * 4);
  int*   cursor = (int*)alloc((size_t)(N + 1) * 4);
  int*   srcs   = (int*)alloc((size_t)E * 4);
  float* norms  = (float*)alloc((size_t)E * 4);
  int*   bar    = (int*)alloc(256);
  float* out    = (float*)d_out;

  hipMemsetAsync(bar, 0, 256, stream);
  k_mega<<<GRID, 256, 0, stream>>>(
      x, ei, ew, W1, b1, W2, b2, Wres, bres, g1, be1, g2, be2,
      xb, W1t, Wrt, W2t, Sx, h1b, Sh1, deg, cnt, rowptr, cursor,
      srcs, norms, bar, out, N, E);
}

// Round 8
// 261.746 us; speedup vs baseline: 7.9100x; 7.9100x over previous
//
#include <hip/hip_runtime.h>
#include <stdint.h>

// GCN 2-hop, R8: R4-proven pipeline (prep -> scan -> fill -> agg128 ->
// gemm_ln1 -> agg256 -> gemm_ln2), with the two GEMM+LN kernels rewritten as
// 4-wave blocks (16 rows x 256 cols per block, 64-col split per wave, LDS
// A-tile staging + cross-wave LDS LayerNorm). R7's 1-wave fused gather+GEMM
// reverted (post-timing divergence + slower).

constexpr int DIN = 128;
constexpr int DH  = 256;
#define LN_EPS 1e-5f

typedef __attribute__((ext_vector_type(8))) short bf16x8;  // 16 B
typedef __attribute__((ext_vector_type(4))) short bf16x4;  // 8 B
typedef __attribute__((ext_vector_type(4))) float f32x4;

__device__ __forceinline__ short f2bf(float f) {
  union { float f; unsigned u; } v; v.f = f;
  unsigned r = v.u + 0x7fffu + ((v.u >> 16) & 1u);  // RNE
  return (short)(r >> 16);
}
__device__ __forceinline__ float bf2f(short b) {
  union { unsigned u; float f; } v; v.u = ((unsigned)(unsigned short)b) << 16;
  return v.f;
}

// edge_index may be int32 (JAX x64 off) or int64: sample odd 32-bit words of
// the src half; all-zero <=> int64. Call with the wave converged.
__device__ __forceinline__ int probe_m64(const unsigned* ei, int E) {
  int lane = threadIdx.x & 63;
  long long stride = (E >= 64) ? (E / 64) : 1;
  long long li = (long long)lane * stride;
  if (li >= E) li = 0;
  unsigned v = ei[2 * li + 1];
  return __ballot(v != 0u) == 0ull;
}

__device__ __forceinline__ int eidx(const void* ei, long long e, int m64) {
  return m64 ? (int)((const long long*)ei)[e] : ((const int*)ei)[e];
}

// ------- prep: x->bf16 + 3 weight transposes + edge accumulation -------
// deg/cnt memset-0 before this kernel; self-loop +1 added in k_scan.

__global__ __launch_bounds__(256) void k_prep(const float* __restrict__ x,
                                              short* __restrict__ xb,
                                              const float* __restrict__ W1,
                                              const float* __restrict__ Wres,
                                              const float* __restrict__ W2,
                                              short* __restrict__ W1t,
                                              short* __restrict__ Wrt,
                                              short* __restrict__ W2t,
                                              const void* ei,
                                              const float* __restrict__ ew,
                                              float* deg, int* cnt,
                                              int N, int E) {
  const int NXV = N * DIN / 8;
  const int NW  = DIN * DH;              // 32768
  const int NW2 = DH * DH;               // 65536
  int idx = blockIdx.x * 256 + threadIdx.x;
  if (idx < NXV) {
    f32x4 a = ((const f32x4*)x)[idx * 2];
    f32x4 b = ((const f32x4*)x)[idx * 2 + 1];
    bf16x8 o;
    o[0] = f2bf(a[0]); o[1] = f2bf(a[1]); o[2] = f2bf(a[2]); o[3] = f2bf(a[3]);
    o[4] = f2bf(b[0]); o[5] = f2bf(b[1]); o[6] = f2bf(b[2]); o[7] = f2bf(b[3]);
    ((bf16x8*)xb)[idx] = o;
    return;
  }
  idx -= NXV;
  if (idx < NW) {
    int n = idx / DIN, k = idx % DIN;
    W1t[idx] = f2bf(W1[k * DH + n]);
    return;
  }
  idx -= NW;
  if (idx < NW) {
    int n = idx / DIN, k = idx % DIN;
    Wrt[idx] = f2bf(Wres[k * DH + n]);
    return;
  }
  idx -= NW;
  if (idx < NW2) {
    int n = idx / DH, k = idx % DH;
    W2t[idx] = f2bf(W2[k * DH + n]);
    return;
  }
  idx -= NW2;
  int m64 = probe_m64((const unsigned*)ei, E);
  if (idx < E) {
    int d = eidx(ei, (long long)E + idx, m64);
    atomicAdd(&deg[d], ew[idx]);
    atomicAdd(&cnt[d], 1);
  }
}

// ---- single block, single pass: dinv=rsqrt(1+deg); scan cnt->rowptr/cursor --

__global__ __launch_bounds__(1024) void k_scan(const int* __restrict__ cnt,
                                               float* deg, int* rowptr,
                                               int* cursor, int n) {
  for (int i = threadIdx.x; i < n; i += 1024) deg[i] = rsqrtf(1.0f + deg[i]);

  constexpr int MAXI = 32;
  int items = (n + 1023) / 1024;         // 20 for N=20000
  int tid = threadIdx.x, lane = tid & 63, wv = tid >> 6;
  int base = tid * items;
  int v[MAXI];
  int tot = 0;
#pragma unroll 4
  for (int j = 0; j < items; ++j) {
    int i = base + j;
    v[j] = (i < n) ? cnt[i] : 0;
    tot += v[j];
  }
  int sc = tot;
#pragma unroll
  for (int off = 1; off < 64; off <<= 1) {
    int t = __shfl_up(sc, off, 64);
    if (lane >= off) sc += t;
  }
  __shared__ int wsum[16];
  if (lane == 63) wsum[wv] = sc;
  __syncthreads();
  if (wv == 0 && lane < 16) {
    int s = wsum[lane];
#pragma unroll
    for (int off = 1; off < 16; off <<= 1) {
      int t = __shfl_up(s, off, 64);
      if (lane >= off) s += t;
    }
    wsum[lane] = s;
  }
  __syncthreads();
  int prefix = (sc - tot) + ((wv > 0) ? wsum[wv - 1] : 0);
  if (tid == 0) { rowptr[0] = 0; cursor[0] = 0; }
  int run = prefix;
#pragma unroll 4
  for (int j = 0; j < items; ++j) {
    int i = base + j;
    run += v[j];
    if (i < n) { rowptr[i + 1] = run; cursor[i + 1] = run; }
  }
}

// ---------------- CSR fill ----------------

__global__ __launch_bounds__(256) void k_fill(const void* ei,
                                              const float* __restrict__ w,
                                              const float* __restrict__ dinv,
                                              int* cursor, int* srcs,
                                              float* norms, int E) {
  int m64 = probe_m64((const unsigned*)ei, E);
  int e = blockIdx.x * 256 + threadIdx.x;
  if (e >= E) return;
  int s = eidx(ei, e, m64);
  int d = eidx(ei, (long long)E + e, m64);
  int p = atomicAdd(&cursor[d], 1);
  srcs[p] = s;
  norms[p] = dinv[s] * w[e] * dinv[d];
}

// ------- pure gather-aggregate (R4-proven): 4 waves/block, 1 wave/node ------

__global__ __launch_bounds__(256) void k_agg128(const short* __restrict__ T,
                                                const int* __restrict__ rowptr,
                                                const int* __restrict__ srcs,
                                                const float* __restrict__ norms,
                                                const float* __restrict__ dinv,
                                                short* __restrict__ out, int n) {
  int wv = threadIdx.x >> 6, lane = threadIdx.x & 63;
  int i = blockIdx.x * 4 + wv;
  if (i >= n) return;
  int h = lane >> 5;
  int c = (lane & 31) * 4;
  float a0 = 0.f, a1 = 0.f, a2 = 0.f, a3 = 0.f;
  int e = rowptr[i] + h, end = rowptr[i + 1];
  for (; e + 6 < end; e += 8) {
    int s0 = srcs[e], s1 = srcs[e + 2], s2 = srcs[e + 4], s3 = srcs[e + 6];
    float w0 = norms[e], w1 = norms[e + 2], w2 = norms[e + 4], w3 = norms[e + 6];
    bf16x4 v0 = *(const bf16x4*)(T + (long long)s0 * DIN + c);
    bf16x4 v1 = *(const bf16x4*)(T + (long long)s1 * DIN + c);
    bf16x4 v2 = *(const bf16x4*)(T + (long long)s2 * DIN + c);
    bf16x4 v3 = *(const bf16x4*)(T + (long long)s3 * DIN + c);
    a0 += w0 * bf2f(v0[0]) + w1 * bf2f(v1[0]) + w2 * bf2f(v2[0]) + w3 * bf2f(v3[0]);
    a1 += w0 * bf2f(v0[1]) + w1 * bf2f(v1[1]) + w2 * bf2f(v2[1]) + w3 * bf2f(v3[1]);
    a2 += w0 * bf2f(v0[2]) + w1 * bf2f(v1[2]) + w2 * bf2f(v2[2]) + w3 * bf2f(v3[2]);
    a3 += w0 * bf2f(v0[3]) + w1 * bf2f(v1[3]) + w2 * bf2f(v2[3]) + w3 * bf2f(v3[3]);
  }
  for (; e < end; e += 2) {
    int s = srcs[e];
    float w = norms[e];
    bf16x4 v = *(const bf16x4*)(T + (long long)s * DIN + c);
    a0 += w * bf2f(v[0]); a1 += w * bf2f(v[1]);
    a2 += w * bf2f(v[2]); a3 += w * bf2f(v[3]);
  }
  a0 += __shfl_xor(a0, 32, 64); a1 += __shfl_xor(a1, 32, 64);
  a2 += __shfl_xor(a2, 32, 64); a3 += __shfl_xor(a3, 32, 64);
  if (h == 0) {
    float sw = dinv[i] * dinv[i];
    bf16x4 sv = *(const bf16x4*)(T + (long long)i * DIN + c);
    bf16x4 o;
    o[0] = f2bf(a0 + sw * bf2f(sv[0]));
    o[1] = f2bf(a1 + sw * bf2f(sv[1]));
    o[2] = f2bf(a2 + sw * bf2f(sv[2]));
    o[3] = f2bf(a3 + sw * bf2f(sv[3]));
    *(bf16x4*)(out + (long long)i * DIN + c) = o;
  }
}

__global__ __launch_bounds__(256) void k_agg256(const short* __restrict__ T,
                                                const int* __restrict__ rowptr,
                                                const int* __restrict__ srcs,
                                                const float* __restrict__ norms,
                                                const float* __restrict__ dinv,
                                                short* __restrict__ out, int n) {
  int wv = threadIdx.x >> 6, lane = threadIdx.x & 63;
  int i = blockIdx.x * 4 + wv;
  if (i >= n) return;
  int h = lane >> 5;
  int c = (lane & 31) * 8;
  float acc[8];
#pragma unroll
  for (int k = 0; k < 8; ++k) acc[k] = 0.f;
  int e = rowptr[i] + h, end = rowptr[i + 1];
  for (; e + 6 < end; e += 8) {
    int s0 = srcs[e], s1 = srcs[e + 2], s2 = srcs[e + 4], s3 = srcs[e + 6];
    float w0 = norms[e], w1 = norms[e + 2], w2 = norms[e + 4], w3 = norms[e + 6];
    bf16x8 v0 = *(const bf16x8*)(T + (long long)s0 * DH + c);
    bf16x8 v1 = *(const bf16x8*)(T + (long long)s1 * DH + c);
    bf16x8 v2 = *(const bf16x8*)(T + (long long)s2 * DH + c);
    bf16x8 v3 = *(const bf16x8*)(T + (long long)s3 * DH + c);
#pragma unroll
    for (int k = 0; k < 8; ++k)
      acc[k] += w0 * bf2f(v0[k]) + w1 * bf2f(v1[k]) +
                w2 * bf2f(v2[k]) + w3 * bf2f(v3[k]);
  }
  for (; e < end; e += 2) {
    int s = srcs[e];
    float w = norms[e];
    bf16x8 v = *(const bf16x8*)(T + (long long)s * DH + c);
#pragma unroll
    for (int k = 0; k < 8; ++k) acc[k] += w * bf2f(v[k]);
  }
#pragma unroll
  for (int k = 0; k < 8; ++k) acc[k] += __shfl_xor(acc[k], 32, 64);
  if (h == 0) {
    float sw = dinv[i] * dinv[i];
    bf16x8 sv = *(const bf16x8*)(T + (long long)i * DH + c);
    bf16x8 o;
#pragma unroll
    for (int k = 0; k < 8; ++k) o[k] = f2bf(acc[k] + sw * bf2f(sv[k]));
    *(bf16x8*)(out + (long long)i * DH + c) = o;
  }
}

// ------- gemm_ln1: 4-wave block, 16 rows x 256 cols; wave owns 64 cols ------
// h1 = LN(relu(Sx@W1+b1) + x@Wres + bres); A/X tiles in LDS, LN cross-wave.

__global__ __launch_bounds__(256) void k_gemm_ln1(
    const short* __restrict__ Sx, const short* __restrict__ xb,
    const short* __restrict__ W1t, const short* __restrict__ Wrt,
    const float* __restrict__ b1, const float* __restrict__ bres,
    const float* __restrict__ g1, const float* __restrict__ be1,
    short* __restrict__ h1b, int M) {
  __shared__ short As[16][DIN + 8];     // 272B row stride = 17x16B: balanced
  __shared__ short Xs[16][DIN + 8];
  __shared__ float red1[4][16], red2[4][16];
  int tid = threadIdx.x;
  int wv = tid >> 6, lane = tid & 63;
  int lr = lane & 15, lg = lane >> 4;
  int bm = blockIdx.x * 16;

  {  // stage both 16x128 tiles: 256 threads x 1 chunk each
    int row = tid >> 4, ch = tid & 15;
    int gr = min(bm + row, M - 1);
    *(bf16x8*)(&As[row][ch * 8]) = *(const bf16x8*)(Sx + (long long)gr * DIN + ch * 8);
    *(bf16x8*)(&Xs[row][ch * 8]) = *(const bf16x8*)(xb + (long long)gr * DIN + ch * 8);
  }
  __syncthreads();

  f32x4 acc[4] = {};
#pragma unroll
  for (int ks = 0; ks < 4; ++ks) {
    bf16x8 a = *(const bf16x8*)(&As[lr][ks * 32 + lg * 8]);
#pragma unroll
    for (int ni = 0; ni < 4; ++ni) {
      int col = (wv * 4 + ni) * 16 + lr;
      bf16x8 b = *(const bf16x8*)(W1t + col * DIN + ks * 32 + lg * 8);
      acc[ni] = __builtin_amdgcn_mfma_f32_16x16x32_bf16(a, b, acc[ni], 0, 0, 0);
    }
  }
#pragma unroll
  for (int ni = 0; ni < 4; ++ni) {
    int col = (wv * 4 + ni) * 16 + lr;
    float bb = b1[col], br = bres[col];
#pragma unroll
    for (int j = 0; j < 4; ++j)
      acc[ni][j] = fmaxf(acc[ni][j] + bb, 0.f) + br;
  }
#pragma unroll
  for (int ks = 0; ks < 4; ++ks) {
    bf16x8 a = *(const bf16x8*)(&Xs[lr][ks * 32 + lg * 8]);
#pragma unroll
    for (int ni = 0; ni < 4; ++ni) {
      int col = (wv * 4 + ni) * 16 + lr;
      bf16x8 b = *(const bf16x8*)(Wrt + col * DIN + ks * 32 + lg * 8);
      acc[ni] = __builtin_amdgcn_mfma_f32_16x16x32_bf16(a, b, acc[ni], 0, 0, 0);
    }
  }
  // per-wave LN partials (this wave's 64 cols), rows lg*4+j
#pragma unroll
  for (int j = 0; j < 4; ++j) {
    float s1 = acc[0][j] + acc[1][j] + acc[2][j] + acc[3][j];
    float s2 = acc[0][j] * acc[0][j] + acc[1][j] * acc[1][j] +
               acc[2][j] * acc[2][j] + acc[3][j] * acc[3][j];
#pragma unroll
    for (int m = 1; m < 16; m <<= 1) {
      s1 += __shfl_xor(s1, m, 64);
      s2 += __shfl_xor(s2, m, 64);
    }
    if (lr == 0) { red1[wv][lg * 4 + j] = s1; red2[wv][lg * 4 + j] = s2; }
  }
  __syncthreads();
#pragma unroll
  for (int j = 0; j < 4; ++j) {
    int row = lg * 4 + j;
    float s1 = red1[0][row] + red1[1][row] + red1[2][row] + red1[3][row];
    float s2 = red2[0][row] + red2[1][row] + red2[2][row] + red2[3][row];
    float mu = s1 * (1.f / 256.f);
    float rs = rsqrtf(s2 * (1.f / 256.f) - mu * mu + LN_EPS);
    int r = bm + row;
    if (r < M) {
#pragma unroll
      for (int ni = 0; ni < 4; ++ni) {
        int col = (wv * 4 + ni) * 16 + lr;
        float y = (acc[ni][j] - mu) * rs * g1[col] + be1[col];
        h1b[(long long)r * DH + col] = f2bf(y);
      }
    }
  }
}

// ------- gemm_ln2: 4-wave block; out = LN(Sh1@W2 + b2 + h1) (f32) -----------

__global__ __launch_bounds__(256) void k_gemm_ln2(
    const short* __restrict__ Sh1, const short* __restrict__ h1b,
    const short* __restrict__ W2t, const float* __restrict__ b2,
    const float* __restrict__ g2, const float* __restrict__ be2,
    float* __restrict__ out, int M) {
  __shared__ short As[16][DH + 8];      // 528B row stride = 33x16B: balanced
  __shared__ short Hs[16][DH + 8];
  __shared__ float red1[4][16], red2[4][16];
  int tid = threadIdx.x;
  int wv = tid >> 6, lane = tid & 63;
  int lr = lane & 15, lg = lane >> 4;
  int bm = blockIdx.x * 16;

  {  // stage 16x256 tiles: 512 chunks each, 2 per thread
#pragma unroll
    for (int q = 0; q < 2; ++q) {
      int cidx = q * 256 + tid;
      int row = cidx >> 5, ch = cidx & 31;
      int gr = min(bm + row, M - 1);
      *(bf16x8*)(&As[row][ch * 8]) = *(const bf16x8*)(Sh1 + (long long)gr * DH + ch * 8);
      *(bf16x8*)(&Hs[row][ch * 8]) = *(const bf16x8*)(h1b + (long long)gr * DH + ch * 8);
    }
  }
  __syncthreads();

  f32x4 acc[4] = {};
#pragma unroll
  for (int ks = 0; ks < 8; ++ks) {
    bf16x8 a = *(const bf16x8*)(&As[lr][ks * 32 + lg * 8]);
#pragma unroll
    for (int ni = 0; ni < 4; ++ni) {
      int col = (wv * 4 + ni) * 16 + lr;
      bf16x8 b = *(const bf16x8*)(W2t + col * DH + ks * 32 + lg * 8);
      acc[ni] = __builtin_amdgcn_mfma_f32_16x16x32_bf16(a, b, acc[ni], 0, 0, 0);
    }
  }
  // + b2 + residual h1 (from LDS tile)
#pragma unroll
  for (int j = 0; j < 4; ++j) {
    int row = lg * 4 + j;
#pragma unroll
    for (int ni = 0; ni < 4; ++ni) {
      int col = (wv * 4 + ni) * 16 + lr;
      acc[ni][j] += b2[col] + bf2f(Hs[row][col]);
    }
  }
#pragma unroll
  for (int j = 0; j < 4; ++j) {
    float s1 = acc[0][j] + acc[1][j] + acc[2][j] + acc[3][j];
    float s2 = acc[0][j] * acc[0][j] + acc[1][j] * acc[1][j] +
               acc[2][j] * acc[2][j] + acc[3][j] * acc[3][j];
#pragma unroll
    for (int m = 1; m < 16; m <<= 1) {
      s1 += __shfl_xor(s1, m, 64);
      s2 += __shfl_xor(s2, m, 64);
    }
    if (lr == 0) { red1[wv][lg * 4 + j] = s1; red2[wv][lg * 4 + j] = s2; }
  }
  __syncthreads();
#pragma unroll
  for (int j = 0; j < 4; ++j) {
    int row = lg * 4 + j;
    float s1 = red1[0][row] + red1[1][row] + red1[2][row] + red1[3][row];
    float s2 = red2[0][row] + red2[1][row] + red2[2][row] + red2[3][row];
    float mu = s1 * (1.f / 256.f);
    float rs = rsqrtf(s2 * (1.f / 256.f) - mu * mu + LN_EPS);
    int r = bm + row;
    if (r < M) {
#pragma unroll
      for (int ni = 0; ni < 4; ++ni) {
        int col = (wv * 4 + ni) * 16 + lr;
        out[(long long)r * DH + col] = (acc[ni][j] - mu) * rs * g2[col] + be2[col];
      }
    }
  }
}

// ---------------- launcher ----------------

extern "C" void kernel_launch(void* const* d_in, const int* in_sizes, int n_in,
                              void* d_out, int out_size, void* d_ws,
                              size_t ws_size, hipStream_t stream) {
  const float* x    = (const float*)d_in[0];
  const void*  ei   = d_in[1];
  const float* ew   = (const float*)d_in[2];
  const float* W1   = (const float*)d_in[3];
  const float* b1   = (const float*)d_in[4];
  const float* W2   = (const float*)d_in[5];
  const float* b2   = (const float*)d_in[6];
  const float* Wres = (const float*)d_in[7];
  const float* bres = (const float*)d_in[8];
  const float* g1   = (const float*)d_in[9];
  const float* be1  = (const float*)d_in[10];
  const float* g2   = (const float*)d_in[11];
  const float* be2  = (const float*)d_in[12];

  const int N = in_sizes[0] / DIN;
  const int E = in_sizes[2];

  char* ws = (char*)d_ws;
  auto alloc = [&](size_t bytes) -> char* {
    char* p = ws;
    ws += (bytes + 255) & ~(size_t)255;
    return p;
  };
  short* xb     = (short*)alloc((size_t)N * DIN * 2);
  short* W1t    = (short*)alloc((size_t)DIN * DH * 2);
  short* Wrt    = (short*)alloc((size_t)DIN * DH * 2);
  short* W2t    = (short*)alloc((size_t)DH * DH * 2);
  short* Sx     = (short*)alloc((size_t)N * DIN * 2);
  short* h1b    = (short*)alloc((size_t)N * DH * 2);
  short* Sh1    = (short*)alloc((size_t)N * DH * 2);
  int*   cnt    = (int*)alloc((size_t)N * 8);   // cnt[N] + deg[N]
  float* deg    = (float*)(cnt + N);            // becomes dinv in k_scan
  int*   rowptr = (int*)alloc((size_t)(N + 1) * 4);
  int*   cursor = (int*)alloc((size_t)(N + 1) * 4);
  int*   srcs   = (int*)alloc((size_t)E * 4);
  float* norms  = (float*)alloc((size_t)E * 4);

  hipMemsetAsync(cnt, 0, (size_t)N * 8, stream);

  int prep_items = N * DIN / 8 + 2 * DIN * DH + DH * DH + E;
  k_prep<<<(prep_items + 255) / 256, 256, 0, stream>>>(
      x, xb, W1, Wres, W2, W1t, Wrt, W2t, ei, ew, deg, cnt, N, E);
  k_scan<<<1, 1024, 0, stream>>>(cnt, deg, rowptr, cursor, N);
  k_fill<<<(E + 255) / 256, 256, 0, stream>>>(ei, ew, deg, cursor, srcs, norms, E);

  k_agg128<<<(N + 3) / 4, 256, 0, stream>>>(xb, rowptr, srcs, norms, deg, Sx, N);
  const int NB = (N + 15) / 16;          // 1250
  k_gemm_ln1<<<NB, 256, 0, stream>>>(Sx, xb, W1t, Wrt, b1, bres, g1, be1,
                                     h1b, N);
  k_agg256<<<(N + 3) / 4, 256, 0, stream>>>(h1b, rowptr, srcs, norms, deg, Sh1, N);
  k_gemm_ln2<<<NB, 256, 0, stream>>>(Sh1, h1b, W2t, b2, g2, be2,
                                     (float*)d_out, N);
}